// Round 3
// baseline (100.919 us; speedup 1.0000x reference)
//
#include <hip/hip_runtime.h>
#include <math.h>

#define CN    64
#define NN    1024
#define NPAIR 528   // 32x33/2 unordered 32-wide tile pairs (bi<=bj)
#define NCHUNK 8    // h=128 split into 8 chunks of 16

// fast tanh via hardware exp2 + rcp: tanh(x) = 1 - 2/(1+e^{2x})
__device__ __forceinline__ float tanh_fast(float x) {
    float e = __expf(2.0f * x);
    return 1.0f - 2.0f * __builtin_amdgcn_rcpf(e + 1.0f);
}

// ---------------------------------------------------------------------------
// prep: per (h,n) U = tanh(pi+b1[h]), V = tanh(pj); S[h][n] = (U,V).
// ---------------------------------------------------------------------------
__global__ __launch_bounds__(256) void prep_kernel(
    const float* __restrict__ x, const float* __restrict__ W1,
    const float* __restrict__ b1, float2* __restrict__ S)
{
    __shared__ float t_s[2][64];
    const int tid = threadIdx.x;
    const int n0  = blockIdx.x * 2;

    if (tid < 64) {
        float2 xv = *(const float2*)&x[tid * NN + n0];
        t_s[0][tid] = tanh_fast(xv.x);
        t_s[1][tid] = tanh_fast(xv.y);
    }
    __syncthreads();

    const int h  = tid & 127;
    const int nl = tid >> 7;
    const float4* wrow = (const float4*)(W1 + h * (2 * CN));

    float pj[4] = {0.f, 0.f, 0.f, 0.f};
    float pi[4] = {0.f, 0.f, 0.f, 0.f};
#pragma unroll
    for (int c4 = 0; c4 < 16; ++c4) {
        float4 tv = *(const float4*)&t_s[nl][c4 * 4];
        float4 wl = wrow[c4];
        float4 wh = wrow[16 + c4];
        const int s = c4 & 3;
        pj[s] = fmaf(wl.x, tv.x, fmaf(wl.y, tv.y, fmaf(wl.z, tv.z, fmaf(wl.w, tv.w, pj[s]))));
        pi[s] = fmaf(wh.x, tv.x, fmaf(wh.y, tv.y, fmaf(wh.z, tv.z, fmaf(wh.w, tv.w, pi[s]))));
    }
    float pjs = (pj[0] + pj[1]) + (pj[2] + pj[3]);
    float pis = (pi[0] + pi[1]) + (pi[2] + pi[3]);
    float U = tanh_fast(pis + b1[h]);
    float V = tanh_fast(pjs);
    S[h * NN + n0 + nl] = make_float2(U, V);
}

// ---------------------------------------------------------------------------
// pair: symmetric-combined form. For unordered pair (i,j):
//   sym(i,j) = sum_h W2h * (P_i Q_j + P_j Q_i) / ((1+U_i V_j)(1+U_j V_i))
// with P = U+V (W2h folded in), Q = 1+UV.  7 VALU per pair*h + on-the-fly
// P/Q (3/point, amortized over 4x4 register tile).
// Block = 1 wave (64 threads), one 32x32 tile-pair x one 16-h chunk.
// Grid = 528*8 = 4224 equal blocks. Partial (1024 floats) -> ws.
// ---------------------------------------------------------------------------
__global__ __launch_bounds__(64) void pair_kernel(
    const float2* __restrict__ S, const float* __restrict__ W2,
    float* __restrict__ ws)
{
    const int id = blockIdx.x;
    const int pair = id >> 3, chunk = id & 7;
    // triangular decode: pair = r(r+1)/2 + c, c<=r
    int r = (int)((sqrtf(8.f * pair + 1.f) - 1.f) * 0.5f);
    while ((r + 1) * (r + 2) / 2 <= pair) ++r;
    while (r * (r + 1) / 2 > pair) --r;
    const int bi = pair - r * (r + 1) / 2, bj = r;
    const int i0 = bi * 32, j0 = bj * 32, h0 = chunk * 16;

    __shared__ float2 Si[16 * 32];   // 4 KB  [h][i]
    __shared__ float2 Sj[16 * 32];   // 4 KB  [h][j]
    const int lane = threadIdx.x;

    {   // stage: 4 float4 per lane per side, coalesced
        float4* SiF = (float4*)Si;
        float4* SjF = (float4*)Sj;
        const float4* SF = (const float4*)S;
#pragma unroll
        for (int k = 0; k < 4; ++k) {
            int t = k * 64 + lane;
            int row = t >> 4, seg = t & 15;
            SiF[t] = SF[(((h0 + row) * NN + i0) >> 1) + seg];
            SjF[t] = SF[(((h0 + row) * NN + j0) >> 1) + seg];
        }
    }
    __syncthreads();

    const int la = lane & 7, lb = lane >> 3;   // 8x8 lane grid
    float acc[4][4];
#pragma unroll
    for (int m = 0; m < 4; ++m)
#pragma unroll
        for (int n = 0; n < 4; ++n) acc[m][n] = 0.f;

#pragma unroll 4
    for (int h = 0; h < 16; ++h) {
        const float w2h = W2[h0 + h];          // wave-uniform -> s_load
        float2 A[4], B[4];
#pragma unroll
        for (int m = 0; m < 4; ++m) A[m] = Si[h * 32 + la + 8 * m];
#pragma unroll
        for (int n = 0; n < 4; ++n) B[n] = Sj[h * 32 + lb + 8 * n];
        float PA[4], QA[4], PB[4], QB[4];
#pragma unroll
        for (int m = 0; m < 4; ++m) {
            PA[m] = w2h * (A[m].x + A[m].y);
            QA[m] = fmaf(A[m].x, A[m].y, 1.0f);
        }
#pragma unroll
        for (int n = 0; n < 4; ++n) {
            PB[n] = w2h * (B[n].x + B[n].y);
            QB[n] = fmaf(B[n].x, B[n].y, 1.0f);
        }
#pragma unroll
        for (int m = 0; m < 4; ++m)
#pragma unroll
            for (int n = 0; n < 4; ++n) {
                float d1 = fmaf(A[m].x, B[n].y, 1.0f);
                float d2 = fmaf(B[n].x, A[m].y, 1.0f);
                float rr = __builtin_amdgcn_rcpf(d1 * d2);
                float Np = fmaf(PA[m], QB[n], PB[n] * QA[m]);
                acc[m][n] = fmaf(Np, rr, acc[m][n]);
            }
    }

    // partial layout: cell q*64+lane, q = m*4+n -> i = la+8m, j = lb+8n
    float* wsp = ws + (pair * NCHUNK + chunk) * 1024;
#pragma unroll
    for (int m = 0; m < 4; ++m)
#pragma unroll
        for (int n = 0; n < 4; ++n)
            wsp[(m * 4 + n) * 64 + lane] = acc[m][n];   // coalesced dwords
}

// ---------------------------------------------------------------------------
// combine: sum 8 chunk-partials per cell + 2*b2, write tile (+ mirror via
// padded-LDS transpose). 528 blocks x 256 threads.
// ---------------------------------------------------------------------------
__global__ __launch_bounds__(256) void combine_kernel(
    const float* __restrict__ ws, const float* __restrict__ b2,
    float* __restrict__ out)
{
    const int pair = blockIdx.x;
    int r = (int)((sqrtf(8.f * pair + 1.f) - 1.f) * 0.5f);
    while ((r + 1) * (r + 2) / 2 <= pair) ++r;
    while (r * (r + 1) / 2 > pair) --r;
    const int bi = pair - r * (r + 1) / 2, bj = r;
    const int i0 = bi * 32, j0 = bj * 32;

    __shared__ float T[32 * 35];   // stride 35 breaks write/read conflicts
    const int t = threadIdx.x;
    const int lane_p = t & 63, q0 = t >> 6;
    const int la = lane_p & 7, lb = (lane_p >> 3) & 7;
    const float bias2 = 2.0f * b2[0];
    const float* wsp = ws + pair * NCHUNK * 1024;

#pragma unroll
    for (int k = 0; k < 4; ++k) {           // q = q0 + 4k -> m=k, n=q0
        float a = 0.f;
#pragma unroll
        for (int cc = 0; cc < NCHUNK; ++cc)
            a += wsp[cc * 1024 + (q0 + 4 * k) * 64 + lane_p];  // coalesced
        T[(la + 8 * k) * 35 + lb + 8 * q0] = a + bias2;
    }
    __syncthreads();

    const int tx = t & 15, ty = t >> 4;     // 16x16 thread grid
#pragma unroll
    for (int k = 0; k < 4; ++k) {
        int rr2 = ty + (k >> 1) * 16;
        int cc2 = tx + (k & 1) * 16;
        out[(i0 + rr2) * NN + j0 + cc2] = T[rr2 * 35 + cc2];
    }
    if (bi != bj) {
#pragma unroll
        for (int k = 0; k < 4; ++k) {
            int rr2 = ty + (k >> 1) * 16;
            int cc2 = tx + (k & 1) * 16;
            out[(j0 + rr2) * NN + i0 + cc2] = T[cc2 * 35 + rr2];
        }
    }
}

extern "C" void kernel_launch(void* const* d_in, const int* in_sizes, int n_in,
                              void* d_out, int out_size, void* d_ws, size_t ws_size,
                              hipStream_t stream)
{
    const float* x  = (const float*)d_in[0];   // [1,64,1024]
    const float* W1 = (const float*)d_in[1];   // [128,128]
    const float* b1 = (const float*)d_in[2];   // [128]
    const float* W2 = (const float*)d_in[3];   // [128]
    const float* b2 = (const float*)d_in[4];   // [1]
    float* out = (float*)d_out;                // [1,1024,1024] fp32

    float2* S   = (float2*)d_ws;                               // 1 MB
    float*  par = (float*)((char*)d_ws + (size_t)2 * 1024 * 1024); // 17.3 MB

    prep_kernel<<<512, 256, 0, stream>>>(x, W1, b1, S);
    pair_kernel<<<NPAIR * NCHUNK, 64, 0, stream>>>(S, W2, par);
    combine_kernel<<<NPAIR, 256, 0, stream>>>(par, b2, out);
}

// Round 4
// 95.664 us; speedup vs baseline: 1.0549x; 1.0549x over previous
//
#include <hip/hip_runtime.h>
#include <math.h>

#define CN    64
#define NN    1024
#define NPAIR 528   // 32x33/2 unordered 32-wide tile pairs (bi<=bj)

// fast tanh via hardware exp2 + rcp: tanh(x) = 1 - 2/(1+e^{2x})
__device__ __forceinline__ float tanh_fast(float x) {
    float e = __expf(2.0f * x);
    return 1.0f - 2.0f * __builtin_amdgcn_rcpf(e + 1.0f);
}

// ---------------------------------------------------------------------------
// prep: per (h,n) U = tanh(pi+b1[h]), V = tanh(pj); S[h][n] = (U,V).
// ---------------------------------------------------------------------------
__global__ __launch_bounds__(256) void prep_kernel(
    const float* __restrict__ x, const float* __restrict__ W1,
    const float* __restrict__ b1, float2* __restrict__ S)
{
    __shared__ float t_s[2][64];
    const int tid = threadIdx.x;
    const int n0  = blockIdx.x * 2;

    if (tid < 64) {
        float2 xv = *(const float2*)&x[tid * NN + n0];
        t_s[0][tid] = tanh_fast(xv.x);
        t_s[1][tid] = tanh_fast(xv.y);
    }
    __syncthreads();

    const int h  = tid & 127;
    const int nl = tid >> 7;
    const float4* wrow = (const float4*)(W1 + h * (2 * CN));

    float pj[4] = {0.f, 0.f, 0.f, 0.f};
    float pi[4] = {0.f, 0.f, 0.f, 0.f};
#pragma unroll
    for (int c4 = 0; c4 < 16; ++c4) {
        float4 tv = *(const float4*)&t_s[nl][c4 * 4];
        float4 wl = wrow[c4];
        float4 wh = wrow[16 + c4];
        const int s = c4 & 3;
        pj[s] = fmaf(wl.x, tv.x, fmaf(wl.y, tv.y, fmaf(wl.z, tv.z, fmaf(wl.w, tv.w, pj[s]))));
        pi[s] = fmaf(wh.x, tv.x, fmaf(wh.y, tv.y, fmaf(wh.z, tv.z, fmaf(wh.w, tv.w, pi[s]))));
    }
    float pjs = (pj[0] + pj[1]) + (pj[2] + pj[3]);
    float pis = (pi[0] + pi[1]) + (pi[2] + pi[3]);
    float U = tanh_fast(pis + b1[h]);
    float V = tanh_fast(pjs);
    S[h * NN + n0 + nl] = make_float2(U, V);
}

// ---------------------------------------------------------------------------
// pair: one block per unordered tile-pair (bi<=bj), ALL 128 h.
//   sym(i,j) = sum_h W2h*(P_i Q_j + P_j Q_i) / ((1+U_i V_j)(1+U_j V_i))
//   P = W2h*(U+V), Q = 1+UV
// 4 waves split h (32 each); 8x8 lane grid x 4x4 cells per lane; cross-wave
// LDS reduce; final tile + transposed mirror written directly. No ws
// partials, no combine kernel.
// LDS: 64 KB stage [2][128][32] float2, reused post-barrier for the 16 KB
// reduce buffer + 4.4 KB transpose tile.
// ---------------------------------------------------------------------------
__global__ __launch_bounds__(256) void pair_kernel(
    const float2* __restrict__ S, const float* __restrict__ W2,
    const float* __restrict__ b2, float* __restrict__ out)
{
    const int pair = blockIdx.x;
    int r = (int)((sqrtf(8.f * pair + 1.f) - 1.f) * 0.5f);
    while ((r + 1) * (r + 2) / 2 <= pair) ++r;
    while (r * (r + 1) / 2 > pair) --r;
    const int bi = pair - r * (r + 1) / 2, bj = r;
    const int i0 = bi * 32, j0 = bj * 32;

    __shared__ float4 sm4[4096];   // 64 KB
    const int tid = threadIdx.x;

    {   // stage: Si = sm4[0..2047] ([128][32] float2), Sj = sm4[2048..4095]
        const float4* SF = (const float4*)S;   // row h = 512 float4
        const int ci = i0 >> 1, cj = j0 >> 1;
#pragma unroll
        for (int k = 0; k < 8; ++k) {
            int idx = k * 256 + tid;           // 0..2047
            int h = idx >> 4, seg = idx & 15;  // 16 float4 per row
            sm4[idx]        = SF[h * 512 + ci + seg];
            sm4[2048 + idx] = SF[h * 512 + cj + seg];
        }
    }
    __syncthreads();

    const int w = tid >> 6, lane = tid & 63;
    const int la = lane & 7, lb = lane >> 3;
    const float2* Si = (const float2*)sm4;            // [128][32]
    const float2* Sj = (const float2*)(sm4 + 2048);

    float acc[16];
#pragma unroll
    for (int q = 0; q < 16; ++q) acc[q] = 0.f;

    const int hbase = w * 32;
#pragma unroll 4
    for (int hh = 0; hh < 32; ++hh) {
        const int h = hbase + hh;
        const float w2h = W2[h];                      // wave-uniform s_load
        float2 A[4], B[4];
        float PA[4], QA[4], PB[4], QB[4];
#pragma unroll
        for (int m = 0; m < 4; ++m) {
            A[m]  = Si[h * 32 + la + 8 * m];
            PA[m] = w2h * (A[m].x + A[m].y);
            QA[m] = fmaf(A[m].x, A[m].y, 1.0f);
        }
#pragma unroll
        for (int n = 0; n < 4; ++n) {
            B[n]  = Sj[h * 32 + lb + 8 * n];
            PB[n] = w2h * (B[n].x + B[n].y);
            QB[n] = fmaf(B[n].x, B[n].y, 1.0f);
        }
#pragma unroll
        for (int m = 0; m < 4; ++m)
#pragma unroll
            for (int n = 0; n < 4; ++n) {
                float d1 = fmaf(A[m].x, B[n].y, 1.0f);
                float d2 = fmaf(B[n].x, A[m].y, 1.0f);
                float rr = __builtin_amdgcn_rcpf(d1 * d2);
                float Np = fmaf(PB[n], QA[m], PA[m] * QB[n]);
                acc[m * 4 + n] = fmaf(Np, rr, acc[m * 4 + n]);
            }
    }

    __syncthreads();                   // all waves done reading stage
    float* buf = (float*)sm4;          // [4][1024], 16 KB (overlays Si)
#pragma unroll
    for (int q = 0; q < 16; ++q)
        buf[w * 1024 + q * 64 + lane] = acc[q];      // coalesced dwords
    __syncthreads();

    float* T = (float*)(sm4 + 1024);   // 32x34 floats at byte 16K (disjoint)
    const float bias2 = 2.0f * b2[0];
#pragma unroll
    for (int k = 0; k < 4; ++k) {
        int c  = tid + k * 256;        // cell id: q*64 + lane2
        int q  = c >> 6, l2 = c & 63;
        int m = q >> 2, n = q & 3;
        int il = (l2 & 7) + 8 * m, jl = (l2 >> 3) + 8 * n;
        float v = buf[c] + buf[1024 + c] + buf[2048 + c] + buf[3072 + c] + bias2;
        T[il * 34 + jl] = v;           // stride 34: <=2-way bank alias
    }
    __syncthreads();

    const int tx = tid & 15, ty = tid >> 4;
#pragma unroll
    for (int k = 0; k < 4; ++k) {
        int rr2 = ty + (k >> 1) * 16;
        int cc2 = tx + (k & 1) * 16;
        out[(i0 + rr2) * NN + j0 + cc2] = T[rr2 * 34 + cc2];
    }
    if (bi != bj) {
#pragma unroll
        for (int k = 0; k < 4; ++k) {
            int rr2 = ty + (k >> 1) * 16;
            int cc2 = tx + (k & 1) * 16;
            out[(j0 + rr2) * NN + i0 + cc2] = T[cc2 * 34 + rr2];
        }
    }
}

extern "C" void kernel_launch(void* const* d_in, const int* in_sizes, int n_in,
                              void* d_out, int out_size, void* d_ws, size_t ws_size,
                              hipStream_t stream)
{
    const float* x  = (const float*)d_in[0];   // [1,64,1024]
    const float* W1 = (const float*)d_in[1];   // [128,128]
    const float* b1 = (const float*)d_in[2];   // [128]
    const float* W2 = (const float*)d_in[3];   // [128]
    const float* b2 = (const float*)d_in[4];   // [1]
    float* out = (float*)d_out;                // [1,1024,1024] fp32
    float2* S  = (float2*)d_ws;                // 1 MB scratch

    prep_kernel<<<512, 256, 0, stream>>>(x, W1, b1, S);
    pair_kernel<<<NPAIR, 256, 0, stream>>>(S, W2, b2, out);
}

// Round 5
// 90.115 us; speedup vs baseline: 1.1199x; 1.0616x over previous
//
#include <hip/hip_runtime.h>
#include <math.h>

#define CN    64
#define NN    1024
#define NOFF  496   // off-diag 32-wide tile pairs (bi<bj)

// fast tanh via hardware exp2 + rcp: tanh(x) = 1 - 2/(1+e^{2x})
__device__ __forceinline__ float tanh_fast(float x) {
    float e = __expf(2.0f * x);
    return 1.0f - 2.0f * __builtin_amdgcn_rcpf(e + 1.0f);
}

// ---------------------------------------------------------------------------
// prep: per (h,n) U = tanh(pi+b1[h]), V = tanh(pj).
// h-PAIRED layout: S2[hp][n] = float4(U_{2hp}, V_{2hp}, U_{2hp+1}, V_{2hp+1})
// so pair_kernel reads 2 h per ds_read_b128.
// ---------------------------------------------------------------------------
__global__ __launch_bounds__(256) void prep_kernel(
    const float* __restrict__ x, const float* __restrict__ W1,
    const float* __restrict__ b1, float2* __restrict__ S2h)
{
    __shared__ float t_s[2][64];
    const int tid = threadIdx.x;
    const int n0  = blockIdx.x * 2;

    if (tid < 64) {
        float2 xv = *(const float2*)&x[tid * NN + n0];
        t_s[0][tid] = tanh_fast(xv.x);
        t_s[1][tid] = tanh_fast(xv.y);
    }
    __syncthreads();

    const int h  = tid & 127;
    const int nl = tid >> 7;
    const float4* wrow = (const float4*)(W1 + h * (2 * CN));

    float pj[4] = {0.f, 0.f, 0.f, 0.f};
    float pi[4] = {0.f, 0.f, 0.f, 0.f};
#pragma unroll
    for (int c4 = 0; c4 < 16; ++c4) {
        float4 tv = *(const float4*)&t_s[nl][c4 * 4];
        float4 wl = wrow[c4];
        float4 wh = wrow[16 + c4];
        const int s = c4 & 3;
        pj[s] = fmaf(wl.x, tv.x, fmaf(wl.y, tv.y, fmaf(wl.z, tv.z, fmaf(wl.w, tv.w, pj[s]))));
        pi[s] = fmaf(wh.x, tv.x, fmaf(wh.y, tv.y, fmaf(wh.z, tv.z, fmaf(wh.w, tv.w, pi[s]))));
    }
    float pjs = (pj[0] + pj[1]) + (pj[2] + pj[3]);
    float pis = (pi[0] + pi[1]) + (pi[2] + pi[3]);
    float U = tanh_fast(pis + b1[h]);
    float V = tanh_fast(pjs);
    // float2 slot (h&1) of float4 S2[(h>>1)][n]
    S2h[(((h >> 1) * NN) + n0 + nl) * 2 + (h & 1)] = make_float2(U, V);
}

// ---------------------------------------------------------------------------
// pair math: for cell (i,j) and h:  (p=U+V, q=1+UV self, d=1+U V cross)
//   term_h(i,j)+term_h(j,i) = w2h*(p_i q_j + p_j q_i)/((1+U_iV_j)(1+U_jV_i))
// 2-h chain over common denominator: Ne/De + No/Do = (Ne Do + No De)/(De Do)
// -> 13 VALU + 1 rcp per cell per 2h. w2 folded into A-side P,Q.
// ---------------------------------------------------------------------------
__device__ __forceinline__ void cell_term(
    const float4& A, const float4& B,
    float PAe, float QAe, float PAo, float QAo,
    float pBe, float qBe, float pBo, float qBo, float& a)
{
    float d1e = fmaf(A.x, B.y, 1.f);
    float d2e = fmaf(B.x, A.y, 1.f);
    float De  = d1e * d2e;
    float Ne  = fmaf(PAe, qBe, pBe * QAe);
    float d1o = fmaf(A.z, B.w, 1.f);
    float d2o = fmaf(B.z, A.w, 1.f);
    float Do  = d1o * d2o;
    float No  = fmaf(PAo, qBo, pBo * QAo);
    float Num = fmaf(Ne, Do, No * De);
    a = fmaf(Num, __builtin_amdgcn_rcpf(De * Do), a);
}

template<bool DIAG>
__device__ __forceinline__ void run_chunk(
    const float4* __restrict__ Abase, const float4* __restrict__ Bbase,
    const float2* __restrict__ W2p, int hp0, int hp1,
    int la, int lb, float* acc)
{
#pragma unroll 2
    for (int hp = hp0; hp < hp1; ++hp) {
        const float2 w2 = W2p[hp];          // wave-uniform -> s_load
        float4 A[4], B[4];
        float PAe[4], QAe[4], PAo[4], QAo[4];
        float pBe[4], qBe[4], pBo[4], qBo[4];
#pragma unroll
        for (int m = 0; m < 4; ++m) {
            A[m]   = Abase[hp * 32 + la + 8 * m];
            PAe[m] = w2.x * (A[m].x + A[m].y);
            QAe[m] = w2.x * fmaf(A[m].x, A[m].y, 1.f);
            PAo[m] = w2.y * (A[m].z + A[m].w);
            QAo[m] = w2.y * fmaf(A[m].z, A[m].w, 1.f);
        }
#pragma unroll
        for (int n = 0; n < 4; ++n) {
            B[n]   = Bbase[hp * 32 + lb + 8 * n];
            pBe[n] = B[n].x + B[n].y;
            qBe[n] = fmaf(B[n].x, B[n].y, 1.f);
            pBo[n] = B[n].z + B[n].w;
            qBo[n] = fmaf(B[n].z, B[n].w, 1.f);
        }
        if (DIAG) {
            int idx = 0;
#pragma unroll
            for (int m = 0; m < 4; ++m)
#pragma unroll
                for (int n = 0; n < 4; ++n)
                    if (n >= m)
                        cell_term(A[m], B[n], PAe[m], QAe[m], PAo[m], QAo[m],
                                  pBe[n], qBe[n], pBo[n], qBo[n], acc[idx++]);
        } else {
#pragma unroll
            for (int m = 0; m < 4; ++m)
#pragma unroll
                for (int n = 0; n < 4; ++n)
                    cell_term(A[m], B[n], PAe[m], QAe[m], PAo[m], QAo[m],
                              pBe[n], qBe[n], pBo[n], qBo[n], acc[m * 4 + n]);
        }
    }
}

// ---------------------------------------------------------------------------
// pair: 512 blocks x 512 threads (8 waves), 64 KB LDS -> 2 blocks/CU,
// 16 waves/CU (4/SIMD). Blocks 0..15: dual-diagonal (tiles 2k, 2k+1, upper
// 10 cell-blocks each by symmetry). Blocks 16..511: off-diag pair, h split
// 16 per wave, tile + transposed mirror written directly.
// ---------------------------------------------------------------------------
__global__ __launch_bounds__(512, 4) void pair_kernel(
    const float4* __restrict__ S2, const float* __restrict__ W2,
    const float* __restrict__ b2, float* __restrict__ out)
{
    const int id  = blockIdx.x;
    const int tid = threadIdx.x;
    const bool dual = (id < 16);

    int i0, j0;
    if (dual) {                          // tiles d0=2k, d1=2k+1
        i0 = (2 * id) * 32; j0 = (2 * id + 1) * 32;
    } else {                             // p = r(r-1)/2 + c, c<r
        int p = id - 16;
        int r = (int)((1.f + sqrtf(8.f * p + 1.f)) * 0.5f);
        while (r * (r - 1) / 2 > p) --r;
        while (r * (r + 1) / 2 <= p) ++r;
        int c = p - r * (r - 1) / 2;
        i0 = c * 32; j0 = r * 32;
    }

    __shared__ float4 sm[4096];          // 64 KB
    {   // stage: Si=[64 hp][32] float4 at 0, Sj at 2048. Coalesced b128.
#pragma unroll
        for (int k = 0; k < 4; ++k) {
            int idx = k * 512 + tid;     // 0..2047
            int hp = idx >> 5, seg = idx & 31;
            sm[idx]        = S2[hp * NN + i0 + seg];
            sm[2048 + idx] = S2[hp * NN + j0 + seg];
        }
    }
    __syncthreads();

    const int w = tid >> 6, lane = tid & 63;
    const int la = lane & 7, lb = lane >> 3;
    const float4* SiF = sm;
    const float4* SjF = sm + 2048;
    const float2* W2p = (const float2*)W2;

    float acc[16];
#pragma unroll
    for (int q = 0; q < 16; ++q) acc[q] = 0.f;

    if (dual) {
        // wave w: tile s=w>>2 (0->Si, 1->Sj), hp chunk (w&3)*16
        const float4* base = (w < 4) ? SiF : SjF;
        const int hp0 = (w & 3) * 16;
        run_chunk<true>(base, base, W2p, hp0, hp0 + 16, la, lb, acc);
    } else {
        run_chunk<false>(SiF, SjF, W2p, 8 * w, 8 * w + 8, la, lb, acc);
    }

    __syncthreads();                     // stage reads done, overlay LDS
    float* buf = (float*)sm;
    const float bias2 = 2.0f * b2[0];

    if (!dual) {
        // partials: buf[w*1024 + q*64 + lane], 32 KB
#pragma unroll
        for (int q = 0; q < 16; ++q)
            buf[w * 1024 + q * 64 + lane] = acc[q];
        __syncthreads();

        float* T = (float*)sm + 8192;    // 32x34 floats at 32 KB
        for (int c = tid; c < 1024; c += 512) {
            float v = bias2;
#pragma unroll
            for (int wv = 0; wv < 8; ++wv) v += buf[wv * 1024 + c];
            int q = c >> 6, l2 = c & 63;
            int m = q >> 2, n = q & 3;
            T[((l2 & 7) + 8 * m) * 34 + (l2 >> 3) + 8 * n] = v;
        }
        __syncthreads();

        const int tx = tid & 31, ty = tid >> 5;   // 32x16
        out[(i0 + ty)      * NN + j0 + tx] = T[ty * 34 + tx];
        out[(i0 + ty + 16) * NN + j0 + tx] = T[(ty + 16) * 34 + tx];
        out[(j0 + ty)      * NN + i0 + tx] = T[tx * 34 + ty];
        out[(j0 + ty + 16) * NN + i0 + tx] = T[tx * 34 + ty + 16];
    } else {
        // partials: buf[w*640 + q*64 + lane], 20 KB (10 cell-blocks)
#pragma unroll
        for (int q = 0; q < 10; ++q)
            buf[w * 640 + q * 64 + lane] = acc[q];
        __syncthreads();

        float* T0 = (float*)sm + 6144;   // at 24 KB, 32x34
        float* T1 = (float*)sm + 7296;   // at 28.5 KB, 32x34
        for (int c = tid; c < 1280; c += 512) {
            int s = (c >= 640) ? 1 : 0;
            int cc = c - 640 * s;
            float v = bias2;
#pragma unroll
            for (int wv = 0; wv < 4; ++wv) v += buf[(s * 4 + wv) * 640 + cc];
            int qq = cc >> 6, l2 = cc & 63;
            int m = (qq >= 4) + (qq >= 7) + (qq >= 9);
            int start = (m == 0) ? 0 : (m == 1) ? 4 : (m == 2) ? 7 : 9;
            int n = qq - start + m;
            int il = (l2 & 7) + 8 * m, jl = (l2 >> 3) + 8 * n;
            float* T = s ? T1 : T0;
            T[il * 34 + jl] = v;
            if (m != n) T[jl * 34 + il] = v;   // mirror cell-block by symmetry
        }
        __syncthreads();

        const int tx = tid & 31, ty = tid >> 5;
#pragma unroll
        for (int s = 0; s < 2; ++s) {
            const float* T = s ? T1 : T0;
            const int b0 = s ? j0 : i0;        // tile on the diagonal
            out[(b0 + ty)      * NN + b0 + tx] = T[ty * 34 + tx];
            out[(b0 + ty + 16) * NN + b0 + tx] = T[(ty + 16) * 34 + tx];
        }
    }
}

extern "C" void kernel_launch(void* const* d_in, const int* in_sizes, int n_in,
                              void* d_out, int out_size, void* d_ws, size_t ws_size,
                              hipStream_t stream)
{
    const float* x  = (const float*)d_in[0];   // [1,64,1024]
    const float* W1 = (const float*)d_in[1];   // [128,128]
    const float* b1 = (const float*)d_in[2];   // [128]
    const float* W2 = (const float*)d_in[3];   // [128]
    const float* b2 = (const float*)d_in[4];   // [1]
    float* out = (float*)d_out;                // [1,1024,1024] fp32

    float2* S2h = (float2*)d_ws;               // 1 MB: [64 hp][1024 n] float4
    prep_kernel<<<512, 256, 0, stream>>>(x, W1, b1, S2h);
    pair_kernel<<<512, 512, 0, stream>>>((const float4*)d_ws, W2, b2, out);
}